// Round 4
// baseline (1667.970 us; speedup 1.0000x reference)
//
#include <hip/hip_runtime.h>
#include <hip/hip_fp16.h>

#define BB 4
#define CC 3
#define HH 384
#define WW 384
#define HW (HH * WW)
#define NP (BB * HW)
#define KK 5
#define RR 2
#define K2 25
#define NITER 20
#define PADF 2048        // guard floats around each x buffer (max OOB reach is 772)
#define GRID 576         // 4 px/thread, exact cover; must be <= co-resident capacity
#define CPX (GRID / 8)   // 72 blocks per barrier group (bid&7 ~ XCD)

static constexpr float INV_Z2 = 1.0f / (0.15f * 0.15f);

// ---------------------------------------------------------------------------
// Model from R0-R3: per-iteration time is dominated by a fixed ~7-9 us
// dispatch/drain cost (invariant to 4x TLP and to a 42% byte cut). Fix:
// ONE persistent kernel for prep + all 20 iterations. Weights live in 50
// half2 REGISTERS (zero weight memory traffic); x ping-pongs in global with
// a hand-rolled two-level grid barrier (plain launch -- cooperative launch
// failed under graph capture in R2).
//
// Co-residency: __launch_bounds__(256,4) caps VGPR<=128 -> 4 blocks/CU ->
// capacity 1024 >= 576 blocks, LDS=0. All blocks resident => spin barrier
// is safe; a timeout valve turns any residual deadlock into a wrong answer
// (caught by absmax) instead of a hang.
// ---------------------------------------------------------------------------

// barrier area: grp[g] at bar[g*32] (8 groups, 128B apart), mid at bar[256],
// gen at bar[288]. 320 ints total, zeroed by bar_init each launch.
__global__ void bar_init(int* bar) {
    if (threadIdx.x < 320) bar[threadIdx.x] = 0;
}

__device__ __forceinline__ void gbar(int* bar, int myg) {
    __syncthreads();                 // all waves drain their stores to cache
    if (threadIdx.x == 0) {
        int* gen = bar + 288;
        int g = __hip_atomic_load(gen, __ATOMIC_RELAXED, __HIP_MEMORY_SCOPE_AGENT);
        __threadfence();             // release: write-back so other XCDs see our x
        int p = __hip_atomic_fetch_add(bar + myg * 32, 1, __ATOMIC_ACQ_REL,
                                       __HIP_MEMORY_SCOPE_AGENT);
        bool release_done = false;
        if (p == CPX - 1) {          // last of my group
            __hip_atomic_store(bar + myg * 32, 0, __ATOMIC_RELAXED,
                               __HIP_MEMORY_SCOPE_AGENT);
            int q = __hip_atomic_fetch_add(bar + 256, 1, __ATOMIC_ACQ_REL,
                                           __HIP_MEMORY_SCOPE_AGENT);
            if (q == 7) {            // last group: reset mid, bump generation
                __hip_atomic_store(bar + 256, 0, __ATOMIC_RELAXED,
                                   __HIP_MEMORY_SCOPE_AGENT);
                __hip_atomic_fetch_add(gen, 1, __ATOMIC_RELEASE,
                                       __HIP_MEMORY_SCOPE_AGENT);
                release_done = true;
            }
        }
        if (!release_done) {
            int tries = 0;
            while (__hip_atomic_load(gen, __ATOMIC_ACQUIRE,
                                     __HIP_MEMORY_SCOPE_AGENT) == g) {
                __builtin_amdgcn_s_sleep(1);
                if (++tries > (1 << 22)) break;   // safety valve: no hang
            }
        }
        __threadfence();             // acquire: invalidate stale L1/L2 lines
    }
    __syncthreads();
}

__global__ __launch_bounds__(256, 4) void fused_persist(
    const float* __restrict__ img, const float* __restrict__ feat,
    const float* __restrict__ mask, float* __restrict__ xa,
    float* __restrict__ xb, float* __restrict__ out, int* __restrict__ bar)
{
    const int myg  = blockIdx.x & 7;                 // hw round-robin ~ XCD id
    const int sbid = myg * CPX + (blockIdx.x >> 3);  // XCD-chunked pixel mapping
    const int gid  = sbid * 256 + (int)threadIdx.x;
    const int p0   = gid * 4;                        // 576*256*4 == NP exactly
    const int b    = p0 / HW;
    const int rem  = p0 - b * HW;                    // multiple of 4
    const int h    = rem / WW;
    const int wc   = rem - h * WW;
    const size_t bHW = (size_t)b * HW;
    const float* imgb = img + (size_t)b * CC * HW;

    // ---- x0 = feat*mask --------------------------------------------------
    float4 f  = *(const float4*)(feat + bHW + rem);
    float4 mk = *(const float4*)(mask + bHW + rem);
    *(float4*)(xa + bHW + rem) =
        make_float4(f.x * mk.x, f.y * mk.y, f.z * mk.z, f.w * mk.w);

    float v0[4], v1[4], v2[4];
#pragma unroll
    for (int s = 0; s < 4; ++s) {
        v0[s] = imgb[0 * HW + rem + s] + 10.f;
        v1[s] = imgb[1 * HW + rem + s] + 10.f;
        v2[s] = imgb[2 * HW + rem + s] + 10.f;
    }

    // ---- weights once, into registers (R3 numeric profile: unnormalized
    //      half taps, f32 sums, one mask/sz multiply at the end) ----------
    __half2 wA[K2], wB[K2];            // (px0,px1), (px2,px3) per tap
    float sz[4] = {1e-10f, 1e-10f, 1e-10f, 1e-10f};
#pragma unroll
    for (int t = 0; t < K2; ++t) {
        const int dr = t / KK - RR, dc = t % KK - RR;
        const int rr = h + dr;
        float av[4] = {0.f, 0.f, 0.f, 0.f};
#pragma unroll
        for (int s = 0; s < 4; ++s) {
            const int cc2 = wc + s + dc;
            if (rr >= 0 && rr < HH && cc2 >= 0 && cc2 < WW) {
                const int q = rr * WW + cc2;
                float d0 = imgb[0 * HW + q] + 10.f - v0[s];
                float d1 = imgb[1 * HW + q] + 10.f - v1[s];
                float d2 = imgb[2 * HW + q] + 10.f - v2[s];
                av[s] = __expf(-(d0 * d0 + d1 * d1 + d2 * d2) * INV_Z2);
            }
            sz[s] += av[s];
        }
        wA[t] = __floats2half2_rn(av[0], av[1]);
        wB[t] = __floats2half2_rn(av[2], av[3]);
    }
    const float im0 = mk.x * (1.f / sz[0]);
    const float im1 = mk.y * (1.f / sz[1]);
    const float im2 = mk.z * (1.f / sz[2]);
    const float im3 = mk.w * (1.f / sz[3]);

    gbar(bar, myg);                    // x0 visible everywhere

    // ---- 20 iterations, weights in registers, barrier between ------------
    const float* cur = xa;
    float* nxt = xb;
#pragma unroll 1
    for (int it = 0; it < NITER; ++it) {
        float* dst = (it == NITER - 1) ? out : nxt;
        float a0 = 0.f, a1 = 0.f, a2 = 0.f, a3 = 0.f;
#pragma unroll
        for (int dr = 0; dr < KK; ++dr) {
            // row h+dr-2, cols rem-4 .. rem+7: three aligned float4 loads.
            // OOB lands in guards / adjacent rows; weight is exactly 0 there.
            const float* p = cur + bHW + rem + (dr - 2) * WW - 4;
            float xs[12];
#pragma unroll
            for (int q = 0; q < 3; ++q) {
                float4 v = *(const float4*)(p + 4 * q);
                xs[4 * q + 0] = v.x; xs[4 * q + 1] = v.y;
                xs[4 * q + 2] = v.z; xs[4 * q + 3] = v.w;
            }
#pragma unroll
            for (int dc = 0; dc < KK; ++dc) {
                const int t = dr * KK + dc;
                float2 w01 = __half22float2(wA[t]);
                float2 w23 = __half22float2(wB[t]);
                a0 = fmaf(w01.x, xs[dc + 2], a0);
                a1 = fmaf(w01.y, xs[dc + 3], a1);
                a2 = fmaf(w23.x, xs[dc + 4], a2);
                a3 = fmaf(w23.y, xs[dc + 5], a3);
            }
        }
        *(float4*)(dst + bHW + rem) =
            make_float4(a0 * im0, a1 * im1, a2 * im2, a3 * im3);
        if (it != NITER - 1) gbar(bar, myg);
        float* tsw = (float*)cur; cur = nxt; nxt = tsw;
    }
}

extern "C" void kernel_launch(void* const* d_in, const int* in_sizes, int n_in,
                              void* d_out, int out_size, void* d_ws, size_t ws_size,
                              hipStream_t stream)
{
    const float* img  = (const float*)d_in[0];
    const float* feat = (const float*)d_in[1];
    const float* mask = (const float*)d_in[2];
    float* out = (float*)d_out;

    // ws: [ PADF | xa (NP) | PADF | xb (NP) | PADF | barrier (320 ints) ]
    float* base = (float*)d_ws;
    float* xa = base + PADF;
    float* xb = xa + (size_t)NP + PADF;
    int* bar = (int*)(xb + (size_t)NP + PADF);

    bar_init<<<1, 512, 0, stream>>>(bar);
    fused_persist<<<GRID, 256, 0, stream>>>(img, feat, mask, xa, xb, out, bar);
}

// Round 5
// 192.956 us; speedup vs baseline: 8.6443x; 8.6443x over previous
//
#include <hip/hip_runtime.h>
#include <hip/hip_fp16.h>

#define BB 4
#define CC 3
#define HH 384
#define WW 384
#define HW (HH * WW)
#define NP (BB * HW)
#define KK 5
#define RR 2
#define K2 25
#define NITER 20
#define TT 48            // output tile per block
#define KF 4             // fused iterations per launch (5 launches x 4 = 20)
#define LROWS 68         // LDS tile rows: TT + 2*(2*KF + 2)
#define LSTR 72          // LDS row stride (floats): 288 B, 16B-aligned
#define GUARDH 4096      // guard halves around plane array (max OOB reach ~16)
#define PADF 2048
#define PGRID 1152       // prep blocks
#define PCPX (PGRID / 8)
#define IGRID 256        // iter blocks (8x8 tiles x 4 batches)

static constexpr float INV_Z2 = 1.0f / (0.15f * 0.15f);

// ---------------------------------------------------------------------------
// Model (R0-R4): per-iter WORK is ~2.6-4 us; per-dispatch fixed cost ~7-8 us;
// software grid barriers cost ~80 us (agent-scope fences on non-coherent
// XCD L2s). So: pay the dispatch boundary once per KF=4 iterations, and run
// the 4 sub-iterations block-locally in LDS with __syncthreads only.
//
// Validity argument: a launch stages x valid on radius 2*KF=8 around its
// tile (zero-padded outside the image -- exact semantics). Each sub-iter
// computes the full radius-8 region reading through a 2-wide zero ring;
// wrongness creeps inward 2 px per sub-iter, so after 4 sub-iters the tile
// (radius 0) is exact. Out-of-image region pixels compute garbage from
// in-array/guard plane bytes -- finite, and consumed only through weights
// that prep stored as exactly 0.
// ---------------------------------------------------------------------------

// prep: 2 px/thread, writes 25 NORMALIZED, mask-folded fp16 planes
// w[t](p) = mask(p) * a_t(p) / sumz(p)  (OOB taps exactly 0), plus x0.
__global__ __launch_bounds__(256) void prep2(
    const float* __restrict__ img, const float* __restrict__ feat,
    const float* __restrict__ mask, __half* __restrict__ wgt,
    float* __restrict__ x0)
{
    int sbid = (blockIdx.x & 7) * PCPX + (blockIdx.x >> 3);  // XCD-chunked
    int gid = sbid * 256 + threadIdx.x;
    int p0 = gid * 2;
    int b   = p0 / HW;
    int rem = p0 - b * HW;          // even
    int h   = rem / WW;
    int wc  = rem - h * WW;

    const float* imgb = img + (size_t)b * CC * HW;
    const size_t bHW = (size_t)b * HW;

    float2 f  = *(const float2*)(feat + bHW + rem);
    float2 mk = *(const float2*)(mask + bHW + rem);
    *(float2*)(x0 + bHW + rem) = make_float2(f.x * mk.x, f.y * mk.y);

    float v0[2], v1[2], v2[2];
#pragma unroll
    for (int s = 0; s < 2; ++s) {
        v0[s] = imgb[0 * HW + rem + s] + 10.f;
        v1[s] = imgb[1 * HW + rem + s] + 10.f;
        v2[s] = imgb[2 * HW + rem + s] + 10.f;
    }

    float a[2][K2];
    float sz[2] = {1e-10f, 1e-10f};
#pragma unroll
    for (int t = 0; t < K2; ++t) {
        int dr = t / KK - RR, dc = t % KK - RR;
        int rr = h + dr;
#pragma unroll
        for (int s = 0; s < 2; ++s) {
            int cc2 = wc + s + dc;
            float av = 0.f;
            if (rr >= 0 && rr < HH && cc2 >= 0 && cc2 < WW) {
                int q = rr * WW + cc2;
                float d0 = imgb[0 * HW + q] + 10.f - v0[s];
                float d1 = imgb[1 * HW + q] + 10.f - v1[s];
                float d2 = imgb[2 * HW + q] + 10.f - v2[s];
                av = __expf(-(d0 * d0 + d1 * d1 + d2 * d2) * INV_Z2);
            }
            a[s][t] = av;
            sz[s] += av;
        }
    }
    float i0 = mk.x * (1.f / sz[0]);
    float i1 = mk.y * (1.f / sz[1]);
#pragma unroll
    for (int t = 0; t < K2; ++t) {
        __half2 hv = __floats2half2_rn(a[0][t] * i0, a[1][t] * i1);
        *(__half2*)(wgt + ((size_t)b * K2 + t) * HW + rem) = hv;
    }
}

// ---------------------------------------------------------------------------
// One launch = KF=4 fused iterations for one 48x48 tile.
// 512 threads, 8 px/thread over the 64x64 compute region (1 row x 8 cols).
// x double-buffered in LDS; planes re-read from (XCD-local) L2 per sub-iter.
// ---------------------------------------------------------------------------
__global__ __launch_bounds__(512) void iter_tile(
    const __half* __restrict__ wgt, const float* __restrict__ xin,
    float* __restrict__ xout)
{
    __shared__ float buf[2][LROWS][LSTR];
    const int tid = threadIdx.x;
    const int lin = (blockIdx.x & 7) * (IGRID / 8) + (blockIdx.x >> 3);
    const int b  = lin >> 6;            // XCD g owns a contiguous pixel band
    const int ty = (lin >> 3) & 7;      //   matching prep's swizzle
    const int tx = lin & 7;
    const size_t bHW = (size_t)b * HW;

    const int rr = tid >> 3;            // 0..63 region row
    const int ck = tid & 7;             // 0..7 col chunk
    const int relrow = rr - 8;          // -8..55 relative to tile
    const int relc0  = 8 * ck - 8;      // -8..48
    const int grow = ty * TT + relrow;  // -8..391
    const int gcol = tx * TT + relc0;   // -8..391
    const bool rowok = (unsigned)grow < HH;
    const bool colok = (unsigned)gcol < WW;   // 8-chunks fully in or out
    const int lrow = relrow + 10;       // 2..65
    const int lcol = relc0 + 12;        // 4..60 (16B-aligned windows)

    // zero both buffers once; ring cells are never written again
    for (int i = tid; i < 2 * LROWS * LSTR; i += 512)
        ((float*)buf)[i] = 0.f;
    __syncthreads();

    // stage x region (radius 8); OOB rows/cols = 0 == true zero-pad
    float4 xv0 = make_float4(0.f, 0.f, 0.f, 0.f);
    float4 xv1 = make_float4(0.f, 0.f, 0.f, 0.f);
    if (rowok && colok) {
        const float* p = xin + bHW + grow * WW + gcol;
        xv0 = *(const float4*)p;
        xv1 = *(const float4*)(p + 4);
    }
    *(float4*)&buf[0][lrow][lcol]     = xv0;
    *(float4*)&buf[0][lrow][lcol + 4] = xv1;
    __syncthreads();

    const __half* wbase =
        wgt + (size_t)b * K2 * HW + (ptrdiff_t)(grow * WW + gcol);

    int cur = 0;
    float acc[8];
#pragma unroll 1
    for (int j = 0; j < KF; ++j) {
#pragma unroll
        for (int i = 0; i < 8; ++i) acc[i] = 0.f;
        if (rowok) {
#pragma unroll
            for (int dr = 0; dr < KK; ++dr) {
                float xs[16];
#pragma unroll
                for (int q = 0; q < 4; ++q)
                    *(float4*)&xs[4 * q] =
                        *(const float4*)&buf[cur][lrow - 2 + dr][lcol - 4 + 4 * q];
#pragma unroll
                for (int dc = 0; dc < KK; ++dc) {
                    const int t = dr * KK + dc;
                    float4 wv = *(const float4*)(wbase + (size_t)t * HW); // 8 halves
                    const __half2* hp = (const __half2*)&wv;
                    float2 w01 = __half22float2(hp[0]);
                    float2 w23 = __half22float2(hp[1]);
                    float2 w45 = __half22float2(hp[2]);
                    float2 w67 = __half22float2(hp[3]);
                    acc[0] = fmaf(w01.x, xs[dc + 2], acc[0]);
                    acc[1] = fmaf(w01.y, xs[dc + 3], acc[1]);
                    acc[2] = fmaf(w23.x, xs[dc + 4], acc[2]);
                    acc[3] = fmaf(w23.y, xs[dc + 5], acc[3]);
                    acc[4] = fmaf(w45.x, xs[dc + 6], acc[4]);
                    acc[5] = fmaf(w45.y, xs[dc + 7], acc[5]);
                    acc[6] = fmaf(w67.x, xs[dc + 8], acc[6]);
                    acc[7] = fmaf(w67.y, xs[dc + 9], acc[7]);
                }
            }
        }
        *(float4*)&buf[cur ^ 1][lrow][lcol] =
            make_float4(acc[0], acc[1], acc[2], acc[3]);
        *(float4*)&buf[cur ^ 1][lrow][lcol + 4] =
            make_float4(acc[4], acc[5], acc[6], acc[7]);
        cur ^= 1;
        __syncthreads();
    }

    // write back the tile pixels only (each owned by exactly one thread)
    if ((unsigned)relrow < TT && (unsigned)relc0 < TT) {
        float* dst = xout + bHW + grow * WW + gcol;
        *(float4*)dst       = make_float4(acc[0], acc[1], acc[2], acc[3]);
        *(float4*)(dst + 4) = make_float4(acc[4], acc[5], acc[6], acc[7]);
    }
}

extern "C" void kernel_launch(void* const* d_in, const int* in_sizes, int n_in,
                              void* d_out, int out_size, void* d_ws, size_t ws_size,
                              hipStream_t stream)
{
    const float* img  = (const float*)d_in[0];
    const float* feat = (const float*)d_in[1];
    const float* mask = (const float*)d_in[2];
    float* out = (float*)d_out;

    // ws: [ guard | wgt: 25*NP halves (~29.5MB) | guard | xa | pad | xb ]
    __half* wgt = (__half*)d_ws + GUARDH;
    size_t wbytes = ((size_t)GUARDH + (size_t)K2 * NP + GUARDH) * sizeof(__half);
    float* fbase = (float*)((char*)d_ws + ((wbytes + 255) & ~(size_t)255));
    float* xa = fbase + PADF;
    float* xb = xa + (size_t)NP + PADF;

    prep2<<<PGRID, 256, 0, stream>>>(img, feat, mask, wgt, xa);
    iter_tile<<<IGRID, 512, 0, stream>>>(wgt, xa, xb);   // x4
    iter_tile<<<IGRID, 512, 0, stream>>>(wgt, xb, xa);   // x8
    iter_tile<<<IGRID, 512, 0, stream>>>(wgt, xa, xb);   // x12
    iter_tile<<<IGRID, 512, 0, stream>>>(wgt, xb, xa);   // x16
    iter_tile<<<IGRID, 512, 0, stream>>>(wgt, xa, out);  // x20
}